// Round 5
// baseline (2415.233 us; speedup 1.0000x reference)
//
#include <hip/hip_runtime.h>

// ---------------- problem dims ----------------
#define TT   512
#define DIN  1024
#define DH   2048
#define DOUT 1024

// ---------------- launch shape ----------------
#define NWG   256    // WGs 0..127: h1 chain (+epilogue); 128..255: h2 chain
#define HALF  128
#define NTHR  512    // 8 waves; each wave owns 2 h-rows of its chain
#define NSLOT (TT + 1)
#define QSLOT (DH / 2)   // u64 words per slot

typedef unsigned int u32;
typedef unsigned long long u64;

// Records: u32 = f32 bits of h; SENT (NaN pattern) = empty. Stored/loaded in
// ALIGNED u64 PAIRS (each pair = one producer wave's two adjacent rows), so:
//  - producer publishes both rows with ONE atomic u64 store (atomic pair
//    arrival, half the store packets);
//  - consumer polls a slot with TWO unconditional back-to-back u64 loads
//    (its 4 contiguous elements) -> compiler batches the waitcnts -> ONE L3
//    round trip per retry round. (R1/R4's guarded pending-only loads put the
//    check inside each guard -> 4 SERIAL RTs per round; that serialization,
//    not traffic, was the 2.87us/step floor: R4 halved bytes, time flat.)
// Data IS the flag -> no fences; slot-per-step -> no ABA; sentinel re-init
// per run (8.4 MB, ~10us).
#define SENT  0xFFFFFFFFu
#define SENT2 0xFFFFFFFFFFFFFFFFull
__device__ u64 gR1[NSLOT * QSLOT];   // h1 records (u64-pair view)
__device__ u64 gR2[NSLOT * QSLOT];   // h2 records

__device__ __forceinline__ float dot4(float4 a, float4 b) {
  return a.x * b.x + a.y * b.y + a.z * b.z + a.w * b.w;
}
__device__ __forceinline__ float wave_sum(float v) {
  #pragma unroll
  for (int off = 32; off > 0; off >>= 1) v += __shfl_down(v, off, 64);
  return v; // lane 0 holds the sum
}
__device__ __forceinline__ u64 ld64(const u64* p) {
  return __hip_atomic_load((u64*)p, __ATOMIC_RELAXED, __HIP_MEMORY_SCOPE_AGENT);
}
__device__ __forceinline__ void st64(u64* p, u64 v) {
  __hip_atomic_store(p, v, __ATOMIC_RELAXED, __HIP_MEMORY_SCOPE_AGENT);
}
// both halves present? (bitwise & to avoid short-circuit re-serializing waits)
__device__ __forceinline__ bool ok2(u64 q) {
  return ((u32)q != SENT) & ((u32)(q >> 32) != SENT);
}
// Fast tanh, ~3 ulp: only lane 0, 2x per wave per step. Output always
// finite/non-NaN -> can never alias SENT.
__device__ __forceinline__ float fast_tanh(float x) {
  float xc = fminf(fmaxf(x, -9.0f), 9.0f);
  float e  = __expf(2.0f * xc);
  return (e - 1.0f) * __frcp_rn(e + 1.0f);
}
__device__ __forceinline__ void stage4(float* lds, int tid, u64 q0, u64 q1) {
  ((float4*)lds)[tid] = make_float4(
      __uint_as_float((u32)q0), __uint_as_float((u32)(q0 >> 32)),
      __uint_as_float((u32)q1), __uint_as_float((u32)(q1 >> 32)));
}

// Poll one slot: thread tid owns u64 words {2*tid, 2*tid+1} (elements
// 4*tid..4*tid+3, one 16B line-segment). Unconditional reload of both words
// per round (line-granularity traffic identical to pending-only).
__device__ __forceinline__ void poll_stage(const u64* slot, float* lds, int tid) {
  const u64* p = slot + 2 * (size_t)tid;
  u64 q0 = ld64(p), q1 = ld64(p + 1);
  while (!(ok2(q0) & ok2(q1))) {
    __builtin_amdgcn_s_sleep(1);
    q0 = ld64(p); q1 = ld64(p + 1);
  }
  stage4(lds, tid, q0, q1);
}

// Sentinel-fill all records before each run.
__global__ void init_kernel() {
  int i = blockIdx.x * blockDim.x + threadIdx.x;
  int n = gridDim.x * blockDim.x;
  for (int k = i; k < NSLOT * QSLOT; k += n) {
    st64(&gR1[k], SENT2);
    st64(&gR2[k], SENT2);
  }
}

__global__ __launch_bounds__(NTHR, 2)
void rnn2_kernel(const float* __restrict__ X,
                 const float* __restrict__ Wa, const float* __restrict__ ba,
                 const float* __restrict__ Wb, const float* __restrict__ bb,
                 const float* __restrict__ Wc, const float* __restrict__ bc,
                 const float* __restrict__ Wd, const float* __restrict__ bd,
                 const float* __restrict__ Wo, const float* __restrict__ bo,
                 float* __restrict__ out)
{
  const int g   = blockIdx.x;
  const int tid = threadIdx.x;
  const int w   = tid >> 6;   // wave
  const int l   = tid & 63;   // lane

  // Double-buffered staging; one barrier between stage and dot bounds wave
  // skew -> parity-buffer reuse two steps later is race-free.
  __shared__ float sA[2][DH];
  __shared__ float sB[2][DH];

  if (g < HALF) {
    // ================= h1 chain (+ output epilogue) =================
    const int r0 = g * 16 + 2 * w, r1 = r0 + 1;   // my two h1 rows (pair)
    const int qidx = 8 * g + w;                   // their u64 word index
    float4 wA0[4], wA1[4], wB0[8], wB1[8], wO[8];
    {
      const float4* p0 = (const float4*)(Wa + (size_t)r0 * DIN);
      const float4* p1 = (const float4*)(Wa + (size_t)r1 * DIN);
      #pragma unroll
      for (int j = 0; j < 4; ++j) { wA0[j] = p0[l + 64 * j]; wA1[j] = p1[l + 64 * j]; }
    }
    {
      const float4* p0 = (const float4*)(Wb + (size_t)r0 * DH);
      const float4* p1 = (const float4*)(Wb + (size_t)r1 * DH);
      #pragma unroll
      for (int j = 0; j < 8; ++j) { wB0[j] = p0[l + 64 * j]; wB1[j] = p1[l + 64 * j]; }
    }
    const int orow = g * 8 + w;                   // my output row
    {
      const float4* p = (const float4*)(Wo + (size_t)orow * DH);
      #pragma unroll
      for (int j = 0; j < 8; ++j) wO[j] = p[l + 64 * j];
    }
    const float b1_0 = ba[r0] + bb[r0];
    const float b1_1 = ba[r1] + bb[r1];
    const float bo_r = bo[orow];

    for (int t = 1; t <= TT; ++t) {
      // Pre-issue poll round 0 for h1(t-1): in flight during the X-dot.
      const u64* pp = gR1 + (size_t)(t - 1) * QSLOT + 2 * (size_t)tid;
      u64 q0 = 0, q1 = 0;
      if (t > 1) { q0 = ld64(pp); q1 = ld64(pp + 1); }

      // A.x[t-1]: no cross-WG dependency
      float a0 = 0.f, a1 = 0.f;
      {
        const float4* px = (const float4*)(X + (size_t)(t - 1) * DIN);
        #pragma unroll
        for (int j = 0; j < 4; ++j) {
          float4 x4 = px[l + 64 * j];
          a0 += dot4(wA0[j], x4);
          a1 += dot4(wA1[j], x4);
        }
      }

      if (t > 1) {
        while (!(ok2(q0) & ok2(q1))) {
          __builtin_amdgcn_s_sleep(1);
          q0 = ld64(pp); q1 = ld64(pp + 1);
        }
        float* buf = sA[(t - 1) & 1];
        stage4(buf, tid, q0, q1);
        __syncthreads();
        const float4* ph = (const float4*)buf;
        #pragma unroll
        for (int j = 0; j < 8; ++j) {
          float4 h4 = ph[l + 64 * j];
          a0 += dot4(wB0[j], h4);
          a1 += dot4(wB1[j], h4);
        }
      }
      a0 = wave_sum(a0); a1 = wave_sum(a1);
      if (l == 0) {   // publish both rows as ONE atomic u64 pair
        u64 pr = ((u64)__float_as_uint(fast_tanh(a1 + b1_1)) << 32)
               |  (u64)__float_as_uint(fast_tanh(a0 + b1_0));
        st64(gR1 + (size_t)t * QSLOT + qidx, pr);
      }
    }

    // ---- epilogue: out = Wo . h2[TT] + bo (1 row per wave) ----
    poll_stage(gR2 + (size_t)TT * QSLOT, sA[0], tid);
    __syncthreads();
    {
      const float4* ph = (const float4*)sA[0];
      float acc = 0.f;
      #pragma unroll
      for (int j = 0; j < 8; ++j) acc += dot4(wO[j], ph[l + 64 * j]);
      acc = wave_sum(acc);
      if (l == 0) out[orow] = acc + bo_r;
    }
  } else {
    // ========================= h2 chain =========================
    const int gg = g - HALF;
    const int r0 = gg * 16 + 2 * w, r1 = r0 + 1;  // my two h2 rows (pair)
    const int qidx = 8 * gg + w;
    float4 wC0[8], wC1[8], wD0[8], wD1[8];
    {
      const float4* p0 = (const float4*)(Wc + (size_t)r0 * DH);
      const float4* p1 = (const float4*)(Wc + (size_t)r1 * DH);
      #pragma unroll
      for (int j = 0; j < 8; ++j) { wC0[j] = p0[l + 64 * j]; wC1[j] = p1[l + 64 * j]; }
    }
    {
      const float4* p0 = (const float4*)(Wd + (size_t)r0 * DH);
      const float4* p1 = (const float4*)(Wd + (size_t)r1 * DH);
      #pragma unroll
      for (int j = 0; j < 8; ++j) { wD0[j] = p0[l + 64 * j]; wD1[j] = p1[l + 64 * j]; }
    }
    const float b2_0 = bc[r0] + bd[r0];
    const float b2_1 = bc[r1] + bd[r1];

    for (int t = 1; t <= TT; ++t) {
      // Pre-issue h2(t-1) poll round 0: in flight while we consume h1(t)
      // (which the ahead-running h1 chain usually has ready) and do dotC.
      // Only dotD then sits on the h2 recurrence.
      const u64* pb = gR2 + (size_t)(t - 1) * QSLOT + 2 * (size_t)tid;
      u64 qb0 = 0, qb1 = 0;
      if (t > 1) { qb0 = ld64(pb); qb1 = ld64(pb + 1); }

      float* bufA = sA[t & 1];
      float* bufB = sB[t & 1];
      poll_stage(gR1 + (size_t)t * QSLOT, bufA, tid);
      __syncthreads();

      float a0 = 0.f, a1 = 0.f;
      {
        const float4* ph = (const float4*)bufA;
        #pragma unroll
        for (int j = 0; j < 8; ++j) {
          float4 h4 = ph[l + 64 * j];
          a0 += dot4(wC0[j], h4);
          a1 += dot4(wC1[j], h4);
        }
      }
      if (t > 1) {
        while (!(ok2(qb0) & ok2(qb1))) {
          __builtin_amdgcn_s_sleep(1);
          qb0 = ld64(pb); qb1 = ld64(pb + 1);
        }
        stage4(bufB, tid, qb0, qb1);
        __syncthreads();
        const float4* ph = (const float4*)bufB;
        #pragma unroll
        for (int j = 0; j < 8; ++j) {
          float4 h4 = ph[l + 64 * j];
          a0 += dot4(wD0[j], h4);
          a1 += dot4(wD1[j], h4);
        }
      }
      a0 = wave_sum(a0); a1 = wave_sum(a1);
      if (l == 0) {
        u64 pr = ((u64)__float_as_uint(fast_tanh(a1 + b2_1)) << 32)
               |  (u64)__float_as_uint(fast_tanh(a0 + b2_0));
        st64(gR2 + (size_t)t * QSLOT + qidx, pr);
      }
    }
  }
}

extern "C" void kernel_launch(void* const* d_in, const int* in_sizes, int n_in,
                              void* d_out, int out_size, void* d_ws, size_t ws_size,
                              hipStream_t stream)
{
  (void)in_sizes; (void)n_in; (void)out_size; (void)d_ws; (void)ws_size;

  const float* X  = (const float*)d_in[0];
  const float* Wa = (const float*)d_in[1];   // W_i2h1 [H][IN]
  const float* ba = (const float*)d_in[2];
  const float* Wb = (const float*)d_in[3];   // W_h2h1 [H][H]
  const float* bb = (const float*)d_in[4];
  // d_in[5], d_in[6]: W_h2o1 / b_h2o1 — dead code in the reference
  const float* Wc = (const float*)d_in[7];   // W_i2h2 [H][H]
  const float* bc = (const float*)d_in[8];
  const float* Wd = (const float*)d_in[9];   // W_h2h2 [H][H]
  const float* bd = (const float*)d_in[10];
  const float* Wo = (const float*)d_in[11];  // W_h2o2 [OUT][H]
  const float* bo = (const float*)d_in[12];
  float* out = (float*)d_out;

  init_kernel<<<dim3(1024), dim3(256), 0, stream>>>();

  void* args[] = { &X, &Wa, &ba, &Wb, &bb, &Wc, &bc, &Wd, &bd, &Wo, &bo, &out };
  (void)hipLaunchCooperativeKernel((void*)rnn2_kernel, dim3(NWG), dim3(NTHR),
                                   args, 0, stream);
}

// Round 6
// 1801.005 us; speedup vs baseline: 1.3410x; 1.3410x over previous
//
#include <hip/hip_runtime.h>

// ---------------- problem dims ----------------
#define TT   512
#define DIN  1024
#define DH   2048
#define DOUT 1024

// ---------------- launch shape ----------------
#define NWG   256    // WGs 0..127: h1 chain (+epilogue); 128..255: h2 chain
#define HALF  128
#define NTHR  512    // 8 waves; each wave owns 2 h-rows of its chain
#define NSLOT (TT + 1)
#define QSLOT (DH / 2)   // u64 words per slot (1024)

typedef unsigned int u32;
typedef unsigned long long u64;

// Records: u32 = f32 bits of h; SENT (NaN pattern) = empty; tanh output can
// never be NaN -> data IS the readiness flag (one-RT observe, no fences).
// Slot-per-step -> no ABA. Sentinel re-init per run (8.4 MB).
//
// ROUND-5 CHANGE — LINE-MERGED PUBLISH. Evidence R0..R5: every config runs
// at 88-121 GB/s of beyond-L2 bytes (time ~ bytes/100GB/s, saturated pipe).
// Biggest cuttable block: WRITE_SIZE 65.5 MB = 1M fine-grained 8B record
// stores, each dirtying a 64B line (8x amplification). Now each WG deposits
// its 8 waves' 16 values in LDS (atomic counter, no barrier) and the LAST
// wave stores the WHOLE 64B line with one 8-lane coalesced st64 burst:
// 512*256 line-stores = 8.4 MB written instead of 65.5.
// Consumer bonus: thread tid's 4 floats (4tid..4tid+3) now come from ONE
// producer line -> all-or-nothing arrival -> single-guard retry loop
// (2 back-to-back u64 loads, checks after) = pending-only traffic AND
// ~1 RT per round (R1/R4's 4-deep guarded chains serialized; R3/R5's
// unconditional rounds paid 2x+ traffic — this does neither).
#define SENT  0xFFFFFFFFu
#define SENT2 0xFFFFFFFFFFFFFFFFull
__device__ u64 gR1[NSLOT * QSLOT];   // h1 records (u64-pair view)
__device__ u64 gR2[NSLOT * QSLOT];   // h2 records

__device__ __forceinline__ float dot4(float4 a, float4 b) {
  return a.x * b.x + a.y * b.y + a.z * b.z + a.w * b.w;
}
__device__ __forceinline__ float wave_sum(float v) {
  #pragma unroll
  for (int off = 32; off > 0; off >>= 1) v += __shfl_down(v, off, 64);
  return v; // lane 0 holds the sum
}
__device__ __forceinline__ u64 ld64(const u64* p) {
  return __hip_atomic_load((u64*)p, __ATOMIC_RELAXED, __HIP_MEMORY_SCOPE_AGENT);
}
__device__ __forceinline__ void st64(u64* p, u64 v) {
  __hip_atomic_store(p, v, __ATOMIC_RELAXED, __HIP_MEMORY_SCOPE_AGENT);
}
// both halves present? (bitwise & avoids short-circuit re-serialization)
__device__ __forceinline__ bool ok2(u64 q) {
  return ((u32)q != SENT) & ((u32)(q >> 32) != SENT);
}
// Fast tanh, ~3 ulp: lane 0 only, 2x per wave per step. Output always
// finite/non-NaN -> can never alias SENT.
__device__ __forceinline__ float fast_tanh(float x) {
  float xc = fminf(fmaxf(x, -9.0f), 9.0f);
  float e  = __expf(2.0f * xc);
  return (e - 1.0f) * __frcp_rn(e + 1.0f);
}
__device__ __forceinline__ void stage4(float* lds, int tid, u64 q0, u64 q1) {
  ((float4*)lds)[tid] = make_float4(
      __uint_as_float((u32)q0), __uint_as_float((u32)(q0 >> 32)),
      __uint_as_float((u32)q1), __uint_as_float((u32)(q1 >> 32)));
}

// Single-slot poll: thread tid owns u64 words {2tid, 2tid+1} = floats
// 4tid..4tid+3, all inside ONE producer line. Per-lane loop: done lanes
// exit (exec-masked off) -> pending-only traffic; 2 loads issue
// back-to-back, checks after -> ~1 RT per round.
__device__ __forceinline__ void poll_line(const u64* slot, float* lds, int tid) {
  const u64* p = slot + 2 * (size_t)tid;
  u64 q0 = ld64(p), q1 = ld64(p + 1);
  __builtin_amdgcn_sched_barrier(0);
  bool d = ok2(q0) & ok2(q1);
  while (!d) {
    __builtin_amdgcn_s_sleep(1);
    q0 = ld64(p); q1 = ld64(p + 1);
    __builtin_amdgcn_sched_barrier(0);
    d = ok2(q0) & ok2(q1);
  }
  stage4(lds, tid, q0, q1);
}

// Dual-slot poll (h2 chain: h1[t] and h2[t-1]): both slots' loads issued
// before any check (sched_barrier fences the checks behind all 4 loads).
__device__ __forceinline__ void poll_line2(const u64* sa, const u64* sb,
                                           float* la, float* lb, int tid) {
  const u64* pa = sa + 2 * (size_t)tid;
  const u64* pb = sb + 2 * (size_t)tid;
  u64 qa0 = ld64(pa), qa1 = ld64(pa + 1);
  u64 qb0 = ld64(pb), qb1 = ld64(pb + 1);
  __builtin_amdgcn_sched_barrier(0);
  bool da = ok2(qa0) & ok2(qa1);
  bool db = ok2(qb0) & ok2(qb1);
  while (!(da & db)) {
    __builtin_amdgcn_s_sleep(1);
    if (!da) { qa0 = ld64(pa); qa1 = ld64(pa + 1); }
    if (!db) { qb0 = ld64(pb); qb1 = ld64(pb + 1); }
    __builtin_amdgcn_sched_barrier(0);
    da = ok2(qa0) & ok2(qa1);
    db = ok2(qb0) & ok2(qb1);
  }
  stage4(la, tid, qa0, qa1);
  stage4(lb, tid, qb0, qb1);
}

// Line-merged publish: each wave's lane 0 deposits its two tanh outputs in
// LDS and bumps the counter; the wave that sees old==7 (last) resets the
// counter and stores the full 64B line via lanes 0..7 (one coalesced
// packet). Counter parity reuse at t+2 is fenced by the step-t+1 barrier.
__device__ __forceinline__ void publish16(volatile u32* sPub, u32* sCnt,
                                          float s0, float s1,
                                          u64* dstLine, int w, int l) {
  u32 old = 0;
  if (l == 0) {
    sPub[2 * w    ] = __float_as_uint(fast_tanh(s0));
    sPub[2 * w + 1] = __float_as_uint(fast_tanh(s1));
    old = atomicAdd(sCnt, 1u);
  }
  old = __shfl(old, 0, 64);
  if (old == 7u) {             // I'm the last wave: fire the line
    if (l == 0) *sCnt = 0u;
    if (l < 8) {
      u64 pr = ((u64)sPub[2 * l + 1] << 32) | (u64)sPub[2 * l];
      st64(dstLine + l, pr);
    }
  }
}

// Sentinel-fill all records before each run.
__global__ void init_kernel() {
  int i = blockIdx.x * blockDim.x + threadIdx.x;
  int n = gridDim.x * blockDim.x;
  for (int k = i; k < NSLOT * QSLOT; k += n) {
    st64(&gR1[k], SENT2);
    st64(&gR2[k], SENT2);
  }
}

__global__ __launch_bounds__(NTHR, 2)
void rnn2_kernel(const float* __restrict__ X,
                 const float* __restrict__ Wa, const float* __restrict__ ba,
                 const float* __restrict__ Wb, const float* __restrict__ bb,
                 const float* __restrict__ Wc, const float* __restrict__ bc,
                 const float* __restrict__ Wd, const float* __restrict__ bd,
                 const float* __restrict__ Wo, const float* __restrict__ bo,
                 float* __restrict__ out)
{
  const int g   = blockIdx.x;
  const int tid = threadIdx.x;
  const int w   = tid >> 6;   // wave
  const int l   = tid & 63;   // lane

  // Double-buffered staging; the one barrier per step between stage and dot
  // bounds wave skew -> parity-buffer reuse two steps later is race-free.
  __shared__ float sA[2][DH];
  __shared__ float sB[2][DH];
  __shared__ u32 sPubU[2][16];   // per-parity publish deposit (16 floats)
  __shared__ u32 sCnt[2];        // per-parity publish counters
  if (tid < 2) sCnt[tid] = 0u;
  __syncthreads();

  if (g < HALF) {
    // ================= h1 chain (+ output epilogue) =================
    const int r0 = g * 16 + 2 * w, r1 = r0 + 1;   // my two h1 rows
    float4 wA0[4], wA1[4], wB0[8], wB1[8], wO[8];
    {
      const float4* p0 = (const float4*)(Wa + (size_t)r0 * DIN);
      const float4* p1 = (const float4*)(Wa + (size_t)r1 * DIN);
      #pragma unroll
      for (int j = 0; j < 4; ++j) { wA0[j] = p0[l + 64 * j]; wA1[j] = p1[l + 64 * j]; }
    }
    {
      const float4* p0 = (const float4*)(Wb + (size_t)r0 * DH);
      const float4* p1 = (const float4*)(Wb + (size_t)r1 * DH);
      #pragma unroll
      for (int j = 0; j < 8; ++j) { wB0[j] = p0[l + 64 * j]; wB1[j] = p1[l + 64 * j]; }
    }
    const int orow = g * 8 + w;                   // my output row
    {
      const float4* p = (const float4*)(Wo + (size_t)orow * DH);
      #pragma unroll
      for (int j = 0; j < 8; ++j) wO[j] = p[l + 64 * j];
    }
    const float b1_0 = ba[r0] + bb[r0];
    const float b1_1 = ba[r1] + bb[r1];
    const float bo_r = bo[orow];

    for (int t = 1; t <= TT; ++t) {
      // A.x[t-1]: no cross-WG dependency — compute before the wait
      float a0 = 0.f, a1 = 0.f;
      {
        const float4* px = (const float4*)(X + (size_t)(t - 1) * DIN);
        #pragma unroll
        for (int j = 0; j < 4; ++j) {
          float4 x4 = px[l + 64 * j];
          a0 += dot4(wA0[j], x4);
          a1 += dot4(wA1[j], x4);
        }
      }
      if (t > 1) {
        float* buf = sA[(t - 1) & 1];
        poll_line(gR1 + (size_t)(t - 1) * QSLOT, buf, tid);
        __syncthreads();
        const float4* ph = (const float4*)buf;
        #pragma unroll
        for (int j = 0; j < 8; ++j) {
          float4 h4 = ph[l + 64 * j];
          a0 += dot4(wB0[j], h4);
          a1 += dot4(wB1[j], h4);
        }
      }
      a0 = wave_sum(a0); a1 = wave_sum(a1);
      publish16(sPubU[t & 1], &sCnt[t & 1], a0 + b1_0, a1 + b1_1,
                gR1 + (size_t)t * QSLOT + 8 * g, w, l);
    }

    // ---- epilogue: out = Wo . h2[TT] + bo (1 row per wave) ----
    // sA[0] parity != the loop's last dot buffer (sA[1]) -> race-free.
    poll_line(gR2 + (size_t)TT * QSLOT, sA[0], tid);
    __syncthreads();
    {
      const float4* ph = (const float4*)sA[0];
      float acc = 0.f;
      #pragma unroll
      for (int j = 0; j < 8; ++j) acc += dot4(wO[j], ph[l + 64 * j]);
      acc = wave_sum(acc);
      if (l == 0) out[orow] = acc + bo_r;
    }
  } else {
    // ========================= h2 chain =========================
    const int gg = g - HALF;
    const int r0 = gg * 16 + 2 * w, r1 = r0 + 1;  // my two h2 rows
    float4 wC0[8], wC1[8], wD0[8], wD1[8];
    {
      const float4* p0 = (const float4*)(Wc + (size_t)r0 * DH);
      const float4* p1 = (const float4*)(Wc + (size_t)r1 * DH);
      #pragma unroll
      for (int j = 0; j < 8; ++j) { wC0[j] = p0[l + 64 * j]; wC1[j] = p1[l + 64 * j]; }
    }
    {
      const float4* p0 = (const float4*)(Wd + (size_t)r0 * DH);
      const float4* p1 = (const float4*)(Wd + (size_t)r1 * DH);
      #pragma unroll
      for (int j = 0; j < 8; ++j) { wD0[j] = p0[l + 64 * j]; wD1[j] = p1[l + 64 * j]; }
    }
    const float b2_0 = bc[r0] + bd[r0];
    const float b2_1 = bc[r1] + bd[r1];

    for (int t = 1; t <= TT; ++t) {
      float* bufA = sA[t & 1];
      float* bufB = sB[t & 1];
      if (t > 1)
        poll_line2(gR1 + (size_t)t * QSLOT,
                   gR2 + (size_t)(t - 1) * QSLOT, bufA, bufB, tid);
      else
        poll_line(gR1 + (size_t)1 * QSLOT, bufA, tid);
      __syncthreads();

      float a0 = 0.f, a1 = 0.f;
      {
        const float4* ph = (const float4*)bufA;
        #pragma unroll
        for (int j = 0; j < 8; ++j) {
          float4 h4 = ph[l + 64 * j];
          a0 += dot4(wC0[j], h4);
          a1 += dot4(wC1[j], h4);
        }
      }
      if (t > 1) {
        const float4* ph = (const float4*)bufB;
        #pragma unroll
        for (int j = 0; j < 8; ++j) {
          float4 h4 = ph[l + 64 * j];
          a0 += dot4(wD0[j], h4);
          a1 += dot4(wD1[j], h4);
        }
      }
      a0 = wave_sum(a0); a1 = wave_sum(a1);
      publish16(sPubU[t & 1], &sCnt[t & 1], a0 + b2_0, a1 + b2_1,
                gR2 + (size_t)t * QSLOT + 8 * gg, w, l);
    }
  }
}

extern "C" void kernel_launch(void* const* d_in, const int* in_sizes, int n_in,
                              void* d_out, int out_size, void* d_ws, size_t ws_size,
                              hipStream_t stream)
{
  (void)in_sizes; (void)n_in; (void)out_size; (void)d_ws; (void)ws_size;

  const float* X  = (const float*)d_in[0];
  const float* Wa = (const float*)d_in[1];   // W_i2h1 [H][IN]
  const float* ba = (const float*)d_in[2];
  const float* Wb = (const float*)d_in[3];   // W_h2h1 [H][H]
  const float* bb = (const float*)d_in[4];
  // d_in[5], d_in[6]: W_h2o1 / b_h2o1 — dead code in the reference
  const float* Wc = (const float*)d_in[7];   // W_i2h2 [H][H]
  const float* bc = (const float*)d_in[8];
  const float* Wd = (const float*)d_in[9];   // W_h2h2 [H][H]
  const float* bd = (const float*)d_in[10];
  const float* Wo = (const float*)d_in[11];  // W_h2o2 [OUT][H]
  const float* bo = (const float*)d_in[12];
  float* out = (float*)d_out;

  init_kernel<<<dim3(1024), dim3(256), 0, stream>>>();

  void* args[] = { &X, &Wa, &ba, &Wb, &bb, &Wc, &bc, &Wd, &bd, &Wo, &bo, &out };
  (void)hipLaunchCooperativeKernel((void*)rnn2_kernel, dim3(NWG), dim3(NTHR),
                                   args, 0, stream);
}